// Round 4
// baseline (478.763 us; speedup 1.0000x reference)
//
#include <hip/hip_runtime.h>
#include <hip/hip_bf16.h>

using bf16 = __hip_bfloat16;
typedef __attribute__((ext_vector_type(8))) short short8;   // 8 bf16 = 4 VGPRs (A/B frag)
typedef __attribute__((ext_vector_type(4))) float floatx4;  // C/D frag

struct alignas(16) bf16x8 { bf16 v[8]; };

#define EPSV 1e-5f
#define R8192 (1.f / 8192.f)

__device__ __forceinline__ float lrelu(float v) { return v >= 0.f ? v : 0.2f * v; }

// convert 8 contiguous f32 -> 8 bf16 packed in a uint4
__device__ __forceinline__ uint4 f8_to_bf8(const float* __restrict__ p) {
    float4 a = ((const float4*)p)[0];
    float4 b = ((const float4*)p)[1];
    bf16x8 r;
    r.v[0] = __float2bfloat16(a.x); r.v[1] = __float2bfloat16(a.y);
    r.v[2] = __float2bfloat16(a.z); r.v[3] = __float2bfloat16(a.w);
    r.v[4] = __float2bfloat16(b.x); r.v[5] = __float2bfloat16(b.y);
    r.v[6] = __float2bfloat16(b.z); r.v[7] = __float2bfloat16(b.w);
    return *(uint4*)&r;
}

// async 16B global -> LDS (direct DMA). LDS dest per thread = base + tid*16,
// linear in tid, so each wave's dests are wave-uniform-base + lane*16 (HW contract).
__device__ __forceinline__ void async16(void* lds, const void* g) {
    __builtin_amdgcn_global_load_lds(
        (const __attribute__((address_space(1))) void*)g,
        (__attribute__((address_space(3))) void*)lds,
        16, 0, 0);
}

// ---------------------------------------------------------------------------
// Index chains + zero the BN sums workspace (replaces hipMemsetAsync dispatch).
// grid 64, block 128. rowidx layout: [4][8192].
__global__ void idx_k(const int* __restrict__ FPS0, const int* __restrict__ FPS1,
                      const int* __restrict__ FPS2, const int* __restrict__ FPS3,
                      int* __restrict__ rowidx, float* __restrict__ sums)
{
    int b = blockIdx.x;    // 64
    int s = threadIdx.x;   // 128
    int m = b * 128 + s;
    // zero sums: [5][2][1024] = 10240 floats
    sums[m] = 0.f;
    if (m < 2048) sums[8192 + m] = 0.f;

    int i3 = FPS3[b * 128 + s];    // [0,256)
    int i2 = FPS2[b * 256 + i3];   // [0,512)
    int i1 = FPS1[b * 512 + i2];   // [0,1024)
    int i0 = FPS0[b * 1024 + i1];  // [0,2048)
    rowidx[0 * 8192 + m] = b * 2048 + i0;
    rowidx[1 * 8192 + m] = b * 1024 + i1;
    rowidx[2 * 8192 + m] = b * 512 + i2;
    rowidx[3 * 8192 + m] = b * 256 + i3;
}

// ---------------------------------------------------------------------------
// Gather + f32->bf16 pre-pass (hoists conversion out of the O(M*N*K) loop).
// slots 0..3: Ab[L] = bf16(f_L[rowidx_L, :])  at 8192*((64<<L)-64)
// slots 4..8: Wb[L] = bf16(w_L)               at 1024*((64<<L)-64)
// grid (2048, 9), block 256; 8 elements/thread; early-exit on overshoot.
__global__ __launch_bounds__(256) void gather_k(
    const float* __restrict__ f0, const float* __restrict__ f1,
    const float* __restrict__ f2, const float* __restrict__ f3,
    const float* __restrict__ w04, const float* __restrict__ w14,
    const float* __restrict__ w24, const float* __restrict__ w34,
    const float* __restrict__ w4,
    const int* __restrict__ rowidx, bf16* __restrict__ Ab, bf16* __restrict__ Wb)
{
    int slot = blockIdx.y;
    size_t e = ((size_t)blockIdx.x * 256 + threadIdx.x) * 8;
    if (slot < 4) {
        int L = slot;
        int lk = 6 + L;                       // log2(K), K = 64<<L
        size_t total = (size_t)8192 << lk;
        if (e >= total) return;
        int K = 1 << lk;
        int row = (int)(e >> lk);
        int col = (int)(e & (size_t)(K - 1));
        const float* src = (L == 0) ? f0 : (L == 1) ? f1 : (L == 2) ? f2 : f3;
        int gr = rowidx[L * 8192 + row];
        uint4 r = f8_to_bf8(src + (size_t)gr * K + col);
        *(uint4*)(Ab + (size_t)8192 * ((64 << L) - 64) + e) = r;
    } else {
        int L = slot - 4;
        int lk = 6 + L;
        size_t total = (size_t)1024 << lk;
        if (e >= total) return;
        const float* src = (L == 0) ? w04 : (L == 1) ? w14 : (L == 2) ? w24
                         : (L == 3) ? w34 : w4;
        uint4 r = f8_to_bf8(src + e);
        *(uint4*)(Wb + (size_t)1024 * ((64 << L) - 64) + e) = r;
    }
}

// ---------------------------------------------------------------------------
// Levels 0..3 GEMM (m97 structure: 128x128 tile, BK=32, 4 waves, width-16
// global_load_lds, fused BN sum/sumsq epilogue) PLUS a copy slice (z==4) that
// streams the bit-exact f0..f3 -> out passthrough under the GEMM's compute.
// grid (64, 8, 5), block 256.
__global__ __launch_bounds__(256) void gemm16_k(
    const bf16* __restrict__ Ab, const bf16* __restrict__ Wb,
    bf16* __restrict__ Ybase, float* __restrict__ sums,
    const float* __restrict__ f0, const float* __restrict__ f1,
    const float* __restrict__ f2, const float* __restrict__ f3,
    float* __restrict__ out)
{
    __shared__ bf16 As[128 * 32];   // linear: required by global_load_lds
    __shared__ bf16 Bs[128 * 32];

    int z = blockIdx.z;
    int tid = threadIdx.x;

    if (z == 4) {
        // ---- copy slice: 512 blocks stream 4 x 33.55 MB f32 passthrough ----
        int flat = blockIdx.y * 64 + blockIdx.x;   // 0..511
        int region = flat >> 7;                    // 128 blocks per region
        const float* src = (region == 0) ? f0 : (region == 1) ? f1
                         : (region == 2) ? f2 : f3;
        float* dst = out + (size_t)region * 8388608;
        size_t o0 = (size_t)(flat & 127) * 65536 + (size_t)tid * 8;
#pragma unroll 4
        for (int it = 0; it < 32; ++it) {
            size_t off = o0 + (size_t)it * 2048;
            uint4 v0 = ((const uint4*)(src + off))[0];
            uint4 v1 = ((const uint4*)(src + off))[1];
            ((uint4*)(dst + off))[0] = v0;
            ((uint4*)(dst + off))[1] = v1;
        }
        return;
    }

    // ---- GEMM path: level L = z, K = 64<<L ----
    int K = 64 << z;
    const bf16* A = Ab + (size_t)8192 * ((64 << z) - 64);
    const bf16* W = Wb + (size_t)1024 * ((64 << z) - 64);
    bf16* Y = Ybase + (size_t)z * (8192 * 1024);
    float* sm = sums + z * 2048;

    int bm = blockIdx.x, bn = blockIdx.y;

    // staging: 16B unit u; row = u>>2 (64B = 32 bf16 per row), k-off = (u&3)*8
    int u0 = tid, u1 = tid + 256;
    int row0 = u0 >> 2, k80 = (u0 & 3) << 3;
    int row1 = u1 >> 2, k81 = (u1 & 3) << 3;
    const bf16* ga0 = A + ((size_t)(bm * 128 + row0) * K + k80);
    const bf16* ga1 = A + ((size_t)(bm * 128 + row1) * K + k81);
    const bf16* gb0 = W + ((size_t)(bn * 128 + row0) * K + k80);
    const bf16* gb1 = W + ((size_t)(bn * 128 + row1) * K + k81);
    bf16* la0 = As + u0 * 8;
    bf16* la1 = As + u1 * 8;
    bf16* lb0 = Bs + u0 * 8;
    bf16* lb1 = Bs + u1 * 8;

    int lane = tid & 63, wave = tid >> 6;
    int wm = (wave >> 1) << 6;       // wave M origin (0/64)
    int wn = (wave & 1) << 6;        // wave N origin (0/64)
    int lm = lane & 15;
    int kq = (lane >> 4) << 3;       // k quad offset in elements (0/8/16/24)

    floatx4 acc[4][4] = {};

    for (int k0 = 0; k0 < K; k0 += 32) {
        async16(la0, ga0);
        async16(la1, ga1);
        async16(lb0, gb0);
        async16(lb1, gb1);
        ga0 += 32; ga1 += 32; gb0 += 32; gb1 += 32;
        __syncthreads();             // compiler drains vmcnt(0) here

        short8 af[4], bfr[4];
#pragma unroll
        for (int i = 0; i < 4; i++) af[i]  = *(const short8*)&As[(wm + i * 16 + lm) * 32 + kq];
#pragma unroll
        for (int j = 0; j < 4; j++) bfr[j] = *(const short8*)&Bs[(wn + j * 16 + lm) * 32 + kq];
#pragma unroll
        for (int i = 0; i < 4; i++)
#pragma unroll
            for (int j = 0; j < 4; j++)
                acc[i][j] = __builtin_amdgcn_mfma_f32_16x16x32_bf16(af[i], bfr[j], acc[i][j], 0, 0, 0);
        __syncthreads();
    }

    // epilogue: C/D layout col=lane&15, row=quad*4+reg (verified m89/m91).
    // Store Y (bf16) + per-channel sum/sumsq of the SAME bf16-rounded values.
    int mrow = (lane >> 4) << 2;
    int ncol = lane & 15;
    float ps[4] = {}, pq[4] = {};
#pragma unroll
    for (int i = 0; i < 4; i++) {
#pragma unroll
        for (int j = 0; j < 4; j++) {
#pragma unroll
            for (int r = 0; r < 4; r++) {
                int m = (bm << 7) + wm + i * 16 + mrow + r;
                int n = (bn << 7) + wn + j * 16 + ncol;
                bf16 bv = __float2bfloat16(acc[i][j][r]);
                Y[(size_t)m * 1024 + n] = bv;
                float v = __bfloat162float(bv);
                ps[j] += v; pq[j] += v * v;
            }
        }
    }
#pragma unroll
    for (int j = 0; j < 4; j++) {
        ps[j] += __shfl_xor(ps[j], 16); ps[j] += __shfl_xor(ps[j], 32);
        pq[j] += __shfl_xor(pq[j], 16); pq[j] += __shfl_xor(pq[j], 32);
    }
    if (lane < 16) {
#pragma unroll
        for (int j = 0; j < 4; j++) {
            int ch = (bn << 7) + wn + (j << 4) + lane;
            atomicAdd(&sm[ch], ps[j]);
            atomicAdd(&sm[1024 + ch], pq[j]);
        }
    }
}

// ---------------------------------------------------------------------------
// Level-4 GEMM: plain (non-cooperative) m97 structure, K=1024.
// Writes Y4 (bf16) + BN sum/sumsq atomics; finalize happens in final2_k across
// a kernel boundary (guaranteed-coherent sums read). grid (64, 8), block 256.
__global__ __launch_bounds__(256) void gemm4_k(
    const bf16* __restrict__ X4, const bf16* __restrict__ W4,
    bf16* __restrict__ Y4, float* __restrict__ sums4)
{
    __shared__ bf16 As[128 * 32];
    __shared__ bf16 Bs[128 * 32];

    int tid = threadIdx.x;
    int bm = blockIdx.x, bn = blockIdx.y;
    const int K = 1024;

    int u0 = tid, u1 = tid + 256;
    int row0 = u0 >> 2, k80 = (u0 & 3) << 3;
    int row1 = u1 >> 2, k81 = (u1 & 3) << 3;
    const bf16* ga0 = X4 + ((size_t)(bm * 128 + row0) * K + k80);
    const bf16* ga1 = X4 + ((size_t)(bm * 128 + row1) * K + k81);
    const bf16* gb0 = W4 + ((size_t)(bn * 128 + row0) * K + k80);
    const bf16* gb1 = W4 + ((size_t)(bn * 128 + row1) * K + k81);
    bf16* la0 = As + u0 * 8;
    bf16* la1 = As + u1 * 8;
    bf16* lb0 = Bs + u0 * 8;
    bf16* lb1 = Bs + u1 * 8;

    int lane = tid & 63, wave = tid >> 6;
    int wm = (wave >> 1) << 6;
    int wn = (wave & 1) << 6;
    int lm = lane & 15;
    int kq = (lane >> 4) << 3;

    floatx4 acc[4][4] = {};

    for (int k0 = 0; k0 < K; k0 += 32) {
        async16(la0, ga0);
        async16(la1, ga1);
        async16(lb0, gb0);
        async16(lb1, gb1);
        ga0 += 32; ga1 += 32; gb0 += 32; gb1 += 32;
        __syncthreads();

        short8 af[4], bfr[4];
#pragma unroll
        for (int i = 0; i < 4; i++) af[i]  = *(const short8*)&As[(wm + i * 16 + lm) * 32 + kq];
#pragma unroll
        for (int j = 0; j < 4; j++) bfr[j] = *(const short8*)&Bs[(wn + j * 16 + lm) * 32 + kq];
#pragma unroll
        for (int i = 0; i < 4; i++)
#pragma unroll
            for (int j = 0; j < 4; j++)
                acc[i][j] = __builtin_amdgcn_mfma_f32_16x16x32_bf16(af[i], bfr[j], acc[i][j], 0, 0, 0);
        __syncthreads();
    }

    int mrow = (lane >> 4) << 2;
    int ncol = lane & 15;
    float ps[4] = {}, pq[4] = {};
#pragma unroll
    for (int i = 0; i < 4; i++) {
#pragma unroll
        for (int j = 0; j < 4; j++) {
#pragma unroll
            for (int r = 0; r < 4; r++) {
                int m = (bm << 7) + wm + i * 16 + mrow + r;
                int n = (bn << 7) + wn + j * 16 + ncol;
                bf16 bv = __float2bfloat16(acc[i][j][r]);
                Y4[(size_t)m * 1024 + n] = bv;
                float v = __bfloat162float(bv);
                ps[j] += v; pq[j] += v * v;
            }
        }
    }
#pragma unroll
    for (int j = 0; j < 4; j++) {
        ps[j] += __shfl_xor(ps[j], 16); ps[j] += __shfl_xor(ps[j], 32);
        pq[j] += __shfl_xor(pq[j], 16); pq[j] += __shfl_xor(pq[j], 32);
    }
    if (lane < 16) {
#pragma unroll
        for (int j = 0; j < 4; j++) {
            int ch = (bn << 7) + wn + (j << 4) + lane;
            atomicAdd(&sums4[ch], ps[j]);
            atomicAdd(&sums4[1024 + ch], pq[j]);
        }
    }
}

// ---------------------------------------------------------------------------
// X4 = f4 + sum_i lrelu(Y_i * sc_i + sh_i), with BN finalize (sums -> sc/sh)
// computed inline per thread (replaces the finalize_k dispatch). Each thread
// owns 8 channels and 4 row-chunks (stride 2M elements) so sc/sh amortize 4x.
// grid 1024, block 256.
__global__ __launch_bounds__(256) void combine_k(
    const bf16* __restrict__ Y0, const bf16* __restrict__ Y1,
    const bf16* __restrict__ Y2, const bf16* __restrict__ Y3,
    const float* __restrict__ f4, const float* __restrict__ sums,
    const float* __restrict__ g04, const float* __restrict__ be04,
    const float* __restrict__ g14, const float* __restrict__ be14,
    const float* __restrict__ g24, const float* __restrict__ be24,
    const float* __restrict__ g34, const float* __restrict__ be34,
    bf16* __restrict__ X4)
{
    size_t base = ((size_t)blockIdx.x * 256 + threadIdx.x) * 8;   // [0, 2M)
    int q0 = (int)((base & 1023) >> 2);     // channel quad (0..254, even)
    const floatx4* sv = (const floatx4*)sums;
    const float* gs[4]  = {g04, g14, g24, g34};
    const float* bes[4] = {be04, be14, be24, be34};

    float sc[4][8], sh[4][8];
#pragma unroll
    for (int br = 0; br < 4; br++) {
        floatx4 s0 = sv[br * 512 + q0],       s1 = sv[br * 512 + q0 + 1];
        floatx4 t0 = sv[br * 512 + 256 + q0], t1 = sv[br * 512 + 256 + q0 + 1];
        floatx4 g0 = ((const floatx4*)gs[br])[q0],  g1 = ((const floatx4*)gs[br])[q0 + 1];
        floatx4 b0 = ((const floatx4*)bes[br])[q0], b1 = ((const floatx4*)bes[br])[q0 + 1];
#pragma unroll
        for (int c = 0; c < 4; c++) {
            float mu = s0[c] * R8192, var = t0[c] * R8192 - mu * mu;
            float s = g0[c] * rsqrtf(var + EPSV);
            sc[br][c] = s; sh[br][c] = b0[c] - mu * s;
            mu = s1[c] * R8192; var = t1[c] * R8192 - mu * mu;
            s = g1[c] * rsqrtf(var + EPSV);
            sc[br][c + 4] = s; sh[br][c + 4] = b1[c] - mu * s;
        }
    }

#pragma unroll
    for (int rr = 0; rr < 4; rr++) {
        size_t e = base + (size_t)rr * 2097152;   // same channels, different rows
        bf16x8 y0 = *(const bf16x8*)(Y0 + e);
        bf16x8 y1 = *(const bf16x8*)(Y1 + e);
        bf16x8 y2 = *(const bf16x8*)(Y2 + e);
        bf16x8 y3 = *(const bf16x8*)(Y3 + e);
        float4 v4a = ((const float4*)(f4 + e))[0];
        float4 v4b = ((const float4*)(f4 + e))[1];
        float v4[8] = {v4a.x, v4a.y, v4a.z, v4a.w, v4b.x, v4b.y, v4b.z, v4b.w};
        bf16x8 o;
#pragma unroll
        for (int k = 0; k < 8; k++) {
            float x = v4[k];
            x += lrelu(__bfloat162float(y0.v[k]) * sc[0][k] + sh[0][k]);
            x += lrelu(__bfloat162float(y1.v[k]) * sc[1][k] + sh[1][k]);
            x += lrelu(__bfloat162float(y2.v[k]) * sc[2][k] + sh[2][k]);
            x += lrelu(__bfloat162float(y3.v[k]) * sc[3][k] + sh[3][k]);
            o.v[k] = __float2bfloat16(x);
        }
        *(bf16x8*)(X4 + e) = o;
    }
}

// ---------------------------------------------------------------------------
// out4 = lrelu(Y4 * sc + sh) + f4, with BN finalize inline (sums4 read across
// a kernel boundary -> coherent). Each thread: 8 channels x 4 row-chunks.
// grid 1024, block 256.
__global__ __launch_bounds__(256) void final2_k(
    const bf16* __restrict__ Y4, const float* __restrict__ f4,
    const float* __restrict__ sums4,
    const float* __restrict__ g4, const float* __restrict__ be4,
    float* __restrict__ out4)
{
    size_t base = ((size_t)blockIdx.x * 256 + threadIdx.x) * 8;   // [0, 2M)
    int q0 = (int)((base & 1023) >> 2);
    const floatx4* sv = (const floatx4*)sums4;
    floatx4 s0 = sv[q0],       s1 = sv[q0 + 1];
    floatx4 t0 = sv[256 + q0], t1 = sv[256 + q0 + 1];
    floatx4 g0 = ((const floatx4*)g4)[q0],  g1 = ((const floatx4*)g4)[q0 + 1];
    floatx4 b0 = ((const floatx4*)be4)[q0], b1 = ((const floatx4*)be4)[q0 + 1];

    float sc[8], sh[8];
#pragma unroll
    for (int c = 0; c < 4; c++) {
        float mu = s0[c] * R8192, var = t0[c] * R8192 - mu * mu;
        float s = g0[c] * rsqrtf(var + EPSV);
        sc[c] = s; sh[c] = b0[c] - mu * s;
        mu = s1[c] * R8192; var = t1[c] * R8192 - mu * mu;
        s = g1[c] * rsqrtf(var + EPSV);
        sc[c + 4] = s; sh[c + 4] = b1[c] - mu * s;
    }

#pragma unroll
    for (int rr = 0; rr < 4; rr++) {
        size_t e = base + (size_t)rr * 2097152;
        bf16x8 y = *(const bf16x8*)(Y4 + e);
        float4 v4a = ((const float4*)(f4 + e))[0];
        float4 v4b = ((const float4*)(f4 + e))[1];
        float v4[8] = {v4a.x, v4a.y, v4a.z, v4a.w, v4b.x, v4b.y, v4b.z, v4b.w};
        float o[8];
#pragma unroll
        for (int k = 0; k < 8; k++) {
            float v = __bfloat162float(y.v[k]) * sc[k] + sh[k];
            o[k] = lrelu(v) + v4[k];
        }
        ((float4*)(out4 + e))[0] = make_float4(o[0], o[1], o[2], o[3]);
        ((float4*)(out4 + e))[1] = make_float4(o[4], o[5], o[6], o[7]);
    }
}

// ---------------------------------------------------------------------------
extern "C" void kernel_launch(void* const* d_in, const int* in_sizes, int n_in,
                              void* d_out, int out_size, void* d_ws, size_t ws_size,
                              hipStream_t stream)
{
    const float* f0 = (const float*)d_in[1];
    const float* f1 = (const float*)d_in[2];
    const float* f2 = (const float*)d_in[3];
    const float* f3 = (const float*)d_in[4];
    const float* f4 = (const float*)d_in[5];
    const int* FPS0 = (const int*)d_in[6];
    const int* FPS1 = (const int*)d_in[7];
    const int* FPS2 = (const int*)d_in[8];
    const int* FPS3 = (const int*)d_in[9];
    const float* w04 = (const float*)d_in[10];
    const float* g04 = (const float*)d_in[12];
    const float* be04 = (const float*)d_in[13];
    const float* w14 = (const float*)d_in[14];
    const float* g14 = (const float*)d_in[16];
    const float* be14 = (const float*)d_in[17];
    const float* w24 = (const float*)d_in[18];
    const float* g24 = (const float*)d_in[20];
    const float* be24 = (const float*)d_in[21];
    const float* w34 = (const float*)d_in[22];
    const float* g34 = (const float*)d_in[24];
    const float* be34 = (const float*)d_in[25];
    const float* w4 = (const float*)d_in[26];
    const float* g4 = (const float*)d_in[28];
    const float* be4 = (const float*)d_in[29];

    float* out = (float*)d_out;

    // workspace: Y0..Y3 bf16, rowidx [4][8192], sums [5][2][1024]
    const size_t YN = (size_t)8192 * 1024;
    bf16* Y0 = (bf16*)d_ws;
    bf16* Y1 = Y0 + YN;
    bf16* Y2 = Y1 + YN;
    bf16* Y3 = Y2 + YN;
    int* rowidx = (int*)(Y3 + YN);
    float* sums = (float*)(rowidx + 4 * 8192);
    bf16* X4 = Y0;   // alias: Y0 consumed elementwise before overwrite (combine_k)
    bf16* Y4 = Y1;   // alias: Y1 dead after combine_k

    // bf16 scratch (gathered A + converted W) in out-region 4: dead until
    // final2_k overwrites it (after gemm4_k's W reads, ordered by kernel boundary).
    float* out4 = out + (size_t)4 * 8388608;
    bf16* Ab = (bf16*)out4;
    bf16* Wb = Ab + (size_t)8192 * 960;
    const bf16* W4 = Wb + (size_t)1024 * 960;   // level-4 weight slice

    if (ws_size < (size_t)(4 * YN * 2 + 4 * 8192 * 4 + 5 * 2048 * 4)) return;

    // 1) index chains + zero sums
    idx_k<<<64, 128, 0, stream>>>(FPS0, FPS1, FPS2, FPS3, rowidx, sums);

    // 2) gather + convert (A levels 0-3, W levels 0-4)
    gather_k<<<dim3(2048, 9), 256, 0, stream>>>(f0, f1, f2, f3,
                                                w04, w14, w24, w34, w4,
                                                rowidx, Ab, Wb);

    // 3) levels 0-3 GEMM + copy passthrough hidden under it
    gemm16_k<<<dim3(64, 8, 5), 256, 0, stream>>>(Ab, Wb, Y0, sums,
                                                 f0, f1, f2, f3, out);

    // 4) combine (inline BN finalize for levels 0-3)
    combine_k<<<1024, 256, 0, stream>>>(Y0, Y1, Y2, Y3, f4, sums,
                                        g04, be04, g14, be14, g24, be24,
                                        g34, be34, X4);

    // 5) level-4 GEMM (plain): Y4 + BN sums
    gemm4_k<<<dim3(64, 8), 256, 0, stream>>>(X4, W4, Y4, sums + 4 * 2048);

    // 6) finalize inline + apply + residual -> f32 out
    final2_k<<<1024, 256, 0, stream>>>(Y4, f4, sums + 4 * 2048, g4, be4, out4);
}

// Round 5
// 469.561 us; speedup vs baseline: 1.0196x; 1.0196x over previous
//
#include <hip/hip_runtime.h>
#include <hip/hip_bf16.h>

using bf16 = __hip_bfloat16;
typedef __attribute__((ext_vector_type(8))) short short8;   // 8 bf16 = 4 VGPRs (A/B frag)
typedef __attribute__((ext_vector_type(4))) float floatx4;  // C/D frag

struct alignas(16) bf16x8 { bf16 v[8]; };

#define EPSV 1e-5f
#define R8192 (1.f / 8192.f)

__device__ __forceinline__ float lrelu(float v) { return v >= 0.f ? v : 0.2f * v; }

// convert 8 contiguous f32 -> 8 bf16 packed in a uint4
__device__ __forceinline__ uint4 f8_to_bf8(const float* __restrict__ p) {
    float4 a = ((const float4*)p)[0];
    float4 b = ((const float4*)p)[1];
    bf16x8 r;
    r.v[0] = __float2bfloat16(a.x); r.v[1] = __float2bfloat16(a.y);
    r.v[2] = __float2bfloat16(a.z); r.v[3] = __float2bfloat16(a.w);
    r.v[4] = __float2bfloat16(b.x); r.v[5] = __float2bfloat16(b.y);
    r.v[6] = __float2bfloat16(b.z); r.v[7] = __float2bfloat16(b.w);
    return *(uint4*)&r;
}

// async 16B global -> LDS (direct DMA). LDS dest per thread = base + tid*16,
// linear in tid, so each wave's dests are wave-uniform-base + lane*16 (HW contract).
__device__ __forceinline__ void async16(void* lds, const void* g) {
    __builtin_amdgcn_global_load_lds(
        (const __attribute__((address_space(1))) void*)g,
        (__attribute__((address_space(3))) void*)lds,
        16, 0, 0);
}

// ---------------------------------------------------------------------------
// Index chains + zero the BN sums workspace (replaces hipMemsetAsync dispatch).
// grid 64, block 128. rowidx layout: [4][8192].
__global__ void idx_k(const int* __restrict__ FPS0, const int* __restrict__ FPS1,
                      const int* __restrict__ FPS2, const int* __restrict__ FPS3,
                      int* __restrict__ rowidx, float* __restrict__ sums)
{
    int b = blockIdx.x;    // 64
    int s = threadIdx.x;   // 128
    int m = b * 128 + s;
    // zero sums: [5][2][1024] = 10240 floats
    sums[m] = 0.f;
    if (m < 2048) sums[8192 + m] = 0.f;

    int i3 = FPS3[b * 128 + s];    // [0,256)
    int i2 = FPS2[b * 256 + i3];   // [0,512)
    int i1 = FPS1[b * 512 + i2];   // [0,1024)
    int i0 = FPS0[b * 1024 + i1];  // [0,2048)
    rowidx[0 * 8192 + m] = b * 2048 + i0;
    rowidx[1 * 8192 + m] = b * 1024 + i1;
    rowidx[2 * 8192 + m] = b * 512 + i2;
    rowidx[3 * 8192 + m] = b * 256 + i3;
}

// ---------------------------------------------------------------------------
// Gather + f32->bf16 pre-pass (hoists conversion out of the O(M*N*K) loop).
// slots 0..3: Ab[L] = bf16(f_L[rowidx_L, :])  at 8192*((64<<L)-64)
// slots 4..8: Wb[L] = bf16(w_L)               at 1024*((64<<L)-64)
// grid (2048, 9), block 256; 8 elements/thread; early-exit on overshoot.
__global__ __launch_bounds__(256) void gather_k(
    const float* __restrict__ f0, const float* __restrict__ f1,
    const float* __restrict__ f2, const float* __restrict__ f3,
    const float* __restrict__ w04, const float* __restrict__ w14,
    const float* __restrict__ w24, const float* __restrict__ w34,
    const float* __restrict__ w4,
    const int* __restrict__ rowidx, bf16* __restrict__ Ab, bf16* __restrict__ Wb)
{
    int slot = blockIdx.y;
    size_t e = ((size_t)blockIdx.x * 256 + threadIdx.x) * 8;
    if (slot < 4) {
        int L = slot;
        int lk = 6 + L;                       // log2(K), K = 64<<L
        size_t total = (size_t)8192 << lk;
        if (e >= total) return;
        int K = 1 << lk;
        int row = (int)(e >> lk);
        int col = (int)(e & (size_t)(K - 1));
        const float* src = (L == 0) ? f0 : (L == 1) ? f1 : (L == 2) ? f2 : f3;
        int gr = rowidx[L * 8192 + row];
        uint4 r = f8_to_bf8(src + (size_t)gr * K + col);
        *(uint4*)(Ab + (size_t)8192 * ((64 << L) - 64) + e) = r;
    } else {
        int L = slot - 4;
        int lk = 6 + L;
        size_t total = (size_t)1024 << lk;
        if (e >= total) return;
        const float* src = (L == 0) ? w04 : (L == 1) ? w14 : (L == 2) ? w24
                         : (L == 3) ? w34 : w4;
        uint4 r = f8_to_bf8(src + e);
        *(uint4*)(Wb + (size_t)1024 * ((64 << L) - 64) + e) = r;
    }
}

// ---------------------------------------------------------------------------
// Levels 0..3 GEMM (m97 structure) + copy passthrough, 1-D grid 2560, block 256.
// Dispatch-order fix: roles are INTERLEAVED (role = lgc%5; 4 = copy slice) so the
// 268 MB copy streams concurrently with GEMM for the whole kernel instead of
// forming a low-occupancy tail (round-4 counters: 22% occ, 2.3 TB/s).
// XCD swizzle (bijective, 2560 = 8*320): each XCD owns one bn panel -> its W
// tiles (245 KB) stay L2-resident.
__global__ __launch_bounds__(256) void gemm16_k(
    const bf16* __restrict__ Ab, const bf16* __restrict__ Wb,
    bf16* __restrict__ Ybase, float* __restrict__ sums,
    const float* __restrict__ f0, const float* __restrict__ f1,
    const float* __restrict__ f2, const float* __restrict__ f3,
    float* __restrict__ out)
{
    __shared__ bf16 As[128 * 32];   // linear: required by global_load_lds
    __shared__ bf16 Bs[128 * 32];

    int tid = threadIdx.x;
    int bid = blockIdx.x;                       // 0..2559
    int lgc = (bid & 7) * 320 + (bid >> 3);     // XCD-contiguous logical id
    int role = lgc % 5;
    int tile = lgc / 5;                         // [0,512)

    if (role == 4) {
        // ---- copy slice: 512 blocks stream 4 x 33.55 MB f32 passthrough ----
        int region = tile >> 7;                 // 128 blocks per region
        const float* src = (region == 0) ? f0 : (region == 1) ? f1
                         : (region == 2) ? f2 : f3;
        float* dst = out + (size_t)region * 8388608;
        size_t o0 = (size_t)(tile & 127) * 65536 + (size_t)tid * 8;
#pragma unroll 4
        for (int it = 0; it < 32; ++it) {
            size_t off = o0 + (size_t)it * 2048;
            uint4 v0 = ((const uint4*)(src + off))[0];
            uint4 v1 = ((const uint4*)(src + off))[1];
            ((uint4*)(dst + off))[0] = v0;
            ((uint4*)(dst + off))[1] = v1;
        }
        return;
    }

    // ---- GEMM path: level L = role, K = 64<<L ----
    int z = role;
    int K = 64 << z;
    const bf16* A = Ab + (size_t)8192 * ((64 << z) - 64);
    const bf16* W = Wb + (size_t)1024 * ((64 << z) - 64);
    bf16* Y = Ybase + (size_t)z * (8192 * 1024);
    float* sm = sums + z * 2048;

    int bm = tile & 63;         // [0,64)
    int bn = tile >> 6;         // [0,8) — constant per XCD after swizzle

    // staging: 16B unit u; row = u>>2 (64B = 32 bf16 per row), k-off = (u&3)*8
    int u0 = tid, u1 = tid + 256;
    int row0 = u0 >> 2, k80 = (u0 & 3) << 3;
    int row1 = u1 >> 2, k81 = (u1 & 3) << 3;
    const bf16* ga0 = A + ((size_t)(bm * 128 + row0) * K + k80);
    const bf16* ga1 = A + ((size_t)(bm * 128 + row1) * K + k81);
    const bf16* gb0 = W + ((size_t)(bn * 128 + row0) * K + k80);
    const bf16* gb1 = W + ((size_t)(bn * 128 + row1) * K + k81);
    bf16* la0 = As + u0 * 8;
    bf16* la1 = As + u1 * 8;
    bf16* lb0 = Bs + u0 * 8;
    bf16* lb1 = Bs + u1 * 8;

    int lane = tid & 63, wave = tid >> 6;
    int wm = (wave >> 1) << 6;       // wave M origin (0/64)
    int wn = (wave & 1) << 6;        // wave N origin (0/64)
    int lm = lane & 15;
    int kq = (lane >> 4) << 3;       // k quad offset in elements (0/8/16/24)

    floatx4 acc[4][4] = {};

    for (int k0 = 0; k0 < K; k0 += 32) {
        async16(la0, ga0);
        async16(la1, ga1);
        async16(lb0, gb0);
        async16(lb1, gb1);
        ga0 += 32; ga1 += 32; gb0 += 32; gb1 += 32;
        __syncthreads();             // compiler drains vmcnt(0) here

        short8 af[4], bfr[4];
#pragma unroll
        for (int i = 0; i < 4; i++) af[i]  = *(const short8*)&As[(wm + i * 16 + lm) * 32 + kq];
#pragma unroll
        for (int j = 0; j < 4; j++) bfr[j] = *(const short8*)&Bs[(wn + j * 16 + lm) * 32 + kq];
#pragma unroll
        for (int i = 0; i < 4; i++)
#pragma unroll
            for (int j = 0; j < 4; j++)
                acc[i][j] = __builtin_amdgcn_mfma_f32_16x16x32_bf16(af[i], bfr[j], acc[i][j], 0, 0, 0);
        __syncthreads();
    }

    // epilogue: C/D layout col=lane&15, row=quad*4+reg (verified m89/m91).
    // Store Y (bf16) + per-channel sum/sumsq of the SAME bf16-rounded values.
    int mrow = (lane >> 4) << 2;
    int ncol = lane & 15;
    float ps[4] = {}, pq[4] = {};
#pragma unroll
    for (int i = 0; i < 4; i++) {
#pragma unroll
        for (int j = 0; j < 4; j++) {
#pragma unroll
            for (int r = 0; r < 4; r++) {
                int m = (bm << 7) + wm + i * 16 + mrow + r;
                int n = (bn << 7) + wn + j * 16 + ncol;
                bf16 bv = __float2bfloat16(acc[i][j][r]);
                Y[(size_t)m * 1024 + n] = bv;
                float v = __bfloat162float(bv);
                ps[j] += v; pq[j] += v * v;
            }
        }
    }
#pragma unroll
    for (int j = 0; j < 4; j++) {
        ps[j] += __shfl_xor(ps[j], 16); ps[j] += __shfl_xor(ps[j], 32);
        pq[j] += __shfl_xor(pq[j], 16); pq[j] += __shfl_xor(pq[j], 32);
    }
    if (lane < 16) {
#pragma unroll
        for (int j = 0; j < 4; j++) {
            int ch = (bn << 7) + wn + (j << 4) + lane;
            atomicAdd(&sm[ch], ps[j]);
            atomicAdd(&sm[1024 + ch], pq[j]);
        }
    }
}

// ---------------------------------------------------------------------------
// Level-4 GEMM: plain m97 structure, K=1024, 1-D grid 512 with XCD swizzle.
// Writes Y4 (bf16) + BN sum/sumsq atomics; finalize in final2_k across a
// kernel boundary (coherent sums read).
__global__ __launch_bounds__(256) void gemm4_k(
    const bf16* __restrict__ X4, const bf16* __restrict__ W4,
    bf16* __restrict__ Y4, float* __restrict__ sums4)
{
    __shared__ bf16 As[128 * 32];
    __shared__ bf16 Bs[128 * 32];

    int tid = threadIdx.x;
    int bid = blockIdx.x;                      // 0..511
    int lgc = (bid & 7) * 64 + (bid >> 3);     // bijective (512 = 8*64)
    int bm = lgc & 63, bn = lgc >> 6;
    const int K = 1024;

    int u0 = tid, u1 = tid + 256;
    int row0 = u0 >> 2, k80 = (u0 & 3) << 3;
    int row1 = u1 >> 2, k81 = (u1 & 3) << 3;
    const bf16* ga0 = X4 + ((size_t)(bm * 128 + row0) * K + k80);
    const bf16* ga1 = X4 + ((size_t)(bm * 128 + row1) * K + k81);
    const bf16* gb0 = W4 + ((size_t)(bn * 128 + row0) * K + k80);
    const bf16* gb1 = W4 + ((size_t)(bn * 128 + row1) * K + k81);
    bf16* la0 = As + u0 * 8;
    bf16* la1 = As + u1 * 8;
    bf16* lb0 = Bs + u0 * 8;
    bf16* lb1 = Bs + u1 * 8;

    int lane = tid & 63, wave = tid >> 6;
    int wm = (wave >> 1) << 6;
    int wn = (wave & 1) << 6;
    int lm = lane & 15;
    int kq = (lane >> 4) << 3;

    floatx4 acc[4][4] = {};

    for (int k0 = 0; k0 < K; k0 += 32) {
        async16(la0, ga0);
        async16(la1, ga1);
        async16(lb0, gb0);
        async16(lb1, gb1);
        ga0 += 32; ga1 += 32; gb0 += 32; gb1 += 32;
        __syncthreads();

        short8 af[4], bfr[4];
#pragma unroll
        for (int i = 0; i < 4; i++) af[i]  = *(const short8*)&As[(wm + i * 16 + lm) * 32 + kq];
#pragma unroll
        for (int j = 0; j < 4; j++) bfr[j] = *(const short8*)&Bs[(wn + j * 16 + lm) * 32 + kq];
#pragma unroll
        for (int i = 0; i < 4; i++)
#pragma unroll
            for (int j = 0; j < 4; j++)
                acc[i][j] = __builtin_amdgcn_mfma_f32_16x16x32_bf16(af[i], bfr[j], acc[i][j], 0, 0, 0);
        __syncthreads();
    }

    int mrow = (lane >> 4) << 2;
    int ncol = lane & 15;
    float ps[4] = {}, pq[4] = {};
#pragma unroll
    for (int i = 0; i < 4; i++) {
#pragma unroll
        for (int j = 0; j < 4; j++) {
#pragma unroll
            for (int r = 0; r < 4; r++) {
                int m = (bm << 7) + wm + i * 16 + mrow + r;
                int n = (bn << 7) + wn + j * 16 + ncol;
                bf16 bv = __float2bfloat16(acc[i][j][r]);
                Y4[(size_t)m * 1024 + n] = bv;
                float v = __bfloat162float(bv);
                ps[j] += v; pq[j] += v * v;
            }
        }
    }
#pragma unroll
    for (int j = 0; j < 4; j++) {
        ps[j] += __shfl_xor(ps[j], 16); ps[j] += __shfl_xor(ps[j], 32);
        pq[j] += __shfl_xor(pq[j], 16); pq[j] += __shfl_xor(pq[j], 32);
    }
    if (lane < 16) {
#pragma unroll
        for (int j = 0; j < 4; j++) {
            int ch = (bn << 7) + wn + (j << 4) + lane;
            atomicAdd(&sums4[ch], ps[j]);
            atomicAdd(&sums4[1024 + ch], pq[j]);
        }
    }
}

// ---------------------------------------------------------------------------
// X4 = f4 + sum_i lrelu(Y_i * sc_i + sh_i), with BN finalize (sums -> sc/sh)
// computed inline per thread. Each thread owns 8 channels and 4 row-chunks
// (stride 2M elements) so sc/sh amortize 4x. grid 1024, block 256.
__global__ __launch_bounds__(256) void combine_k(
    const bf16* __restrict__ Y0, const bf16* __restrict__ Y1,
    const bf16* __restrict__ Y2, const bf16* __restrict__ Y3,
    const float* __restrict__ f4, const float* __restrict__ sums,
    const float* __restrict__ g04, const float* __restrict__ be04,
    const float* __restrict__ g14, const float* __restrict__ be14,
    const float* __restrict__ g24, const float* __restrict__ be24,
    const float* __restrict__ g34, const float* __restrict__ be34,
    bf16* __restrict__ X4)
{
    size_t base = ((size_t)blockIdx.x * 256 + threadIdx.x) * 8;   // [0, 2M)
    int q0 = (int)((base & 1023) >> 2);     // channel quad (0..254, even)
    const floatx4* sv = (const floatx4*)sums;
    const float* gs[4]  = {g04, g14, g24, g34};
    const float* bes[4] = {be04, be14, be24, be34};

    float sc[4][8], sh[4][8];
#pragma unroll
    for (int br = 0; br < 4; br++) {
        floatx4 s0 = sv[br * 512 + q0],       s1 = sv[br * 512 + q0 + 1];
        floatx4 t0 = sv[br * 512 + 256 + q0], t1 = sv[br * 512 + 256 + q0 + 1];
        floatx4 g0 = ((const floatx4*)gs[br])[q0],  g1 = ((const floatx4*)gs[br])[q0 + 1];
        floatx4 b0 = ((const floatx4*)bes[br])[q0], b1 = ((const floatx4*)bes[br])[q0 + 1];
#pragma unroll
        for (int c = 0; c < 4; c++) {
            float mu = s0[c] * R8192, var = t0[c] * R8192 - mu * mu;
            float s = g0[c] * rsqrtf(var + EPSV);
            sc[br][c] = s; sh[br][c] = b0[c] - mu * s;
            mu = s1[c] * R8192; var = t1[c] * R8192 - mu * mu;
            s = g1[c] * rsqrtf(var + EPSV);
            sc[br][c + 4] = s; sh[br][c + 4] = b1[c] - mu * s;
        }
    }

#pragma unroll
    for (int rr = 0; rr < 4; rr++) {
        size_t e = base + (size_t)rr * 2097152;   // same channels, different rows
        bf16x8 y0 = *(const bf16x8*)(Y0 + e);
        bf16x8 y1 = *(const bf16x8*)(Y1 + e);
        bf16x8 y2 = *(const bf16x8*)(Y2 + e);
        bf16x8 y3 = *(const bf16x8*)(Y3 + e);
        float4 v4a = ((const float4*)(f4 + e))[0];
        float4 v4b = ((const float4*)(f4 + e))[1];
        float v4[8] = {v4a.x, v4a.y, v4a.z, v4a.w, v4b.x, v4b.y, v4b.z, v4b.w};
        bf16x8 o;
#pragma unroll
        for (int k = 0; k < 8; k++) {
            float x = v4[k];
            x += lrelu(__bfloat162float(y0.v[k]) * sc[0][k] + sh[0][k]);
            x += lrelu(__bfloat162float(y1.v[k]) * sc[1][k] + sh[1][k]);
            x += lrelu(__bfloat162float(y2.v[k]) * sc[2][k] + sh[2][k]);
            x += lrelu(__bfloat162float(y3.v[k]) * sc[3][k] + sh[3][k]);
            o.v[k] = __float2bfloat16(x);
        }
        *(bf16x8*)(X4 + e) = o;
    }
}

// ---------------------------------------------------------------------------
// out4 = lrelu(Y4 * sc + sh) + f4, with BN finalize inline (sums4 read across
// a kernel boundary -> coherent). Each thread: 8 channels x 4 row-chunks.
// grid 1024, block 256.
__global__ __launch_bounds__(256) void final2_k(
    const bf16* __restrict__ Y4, const float* __restrict__ f4,
    const float* __restrict__ sums4,
    const float* __restrict__ g4, const float* __restrict__ be4,
    float* __restrict__ out4)
{
    size_t base = ((size_t)blockIdx.x * 256 + threadIdx.x) * 8;   // [0, 2M)
    int q0 = (int)((base & 1023) >> 2);
    const floatx4* sv = (const floatx4*)sums4;
    floatx4 s0 = sv[q0],       s1 = sv[q0 + 1];
    floatx4 t0 = sv[256 + q0], t1 = sv[256 + q0 + 1];
    floatx4 g0 = ((const floatx4*)g4)[q0],  g1 = ((const floatx4*)g4)[q0 + 1];
    floatx4 b0 = ((const floatx4*)be4)[q0], b1 = ((const floatx4*)be4)[q0 + 1];

    float sc[8], sh[8];
#pragma unroll
    for (int c = 0; c < 4; c++) {
        float mu = s0[c] * R8192, var = t0[c] * R8192 - mu * mu;
        float s = g0[c] * rsqrtf(var + EPSV);
        sc[c] = s; sh[c] = b0[c] - mu * s;
        mu = s1[c] * R8192; var = t1[c] * R8192 - mu * mu;
        s = g1[c] * rsqrtf(var + EPSV);
        sc[c + 4] = s; sh[c + 4] = b1[c] - mu * s;
    }

#pragma unroll
    for (int rr = 0; rr < 4; rr++) {
        size_t e = base + (size_t)rr * 2097152;
        bf16x8 y = *(const bf16x8*)(Y4 + e);
        float4 v4a = ((const float4*)(f4 + e))[0];
        float4 v4b = ((const float4*)(f4 + e))[1];
        float v4[8] = {v4a.x, v4a.y, v4a.z, v4a.w, v4b.x, v4b.y, v4b.z, v4b.w};
        float o[8];
#pragma unroll
        for (int k = 0; k < 8; k++) {
            float v = __bfloat162float(y.v[k]) * sc[k] + sh[k];
            o[k] = lrelu(v) + v4[k];
        }
        ((float4*)(out4 + e))[0] = make_float4(o[0], o[1], o[2], o[3]);
        ((float4*)(out4 + e))[1] = make_float4(o[4], o[5], o[6], o[7]);
    }
}

// ---------------------------------------------------------------------------
extern "C" void kernel_launch(void* const* d_in, const int* in_sizes, int n_in,
                              void* d_out, int out_size, void* d_ws, size_t ws_size,
                              hipStream_t stream)
{
    const float* f0 = (const float*)d_in[1];
    const float* f1 = (const float*)d_in[2];
    const float* f2 = (const float*)d_in[3];
    const float* f3 = (const float*)d_in[4];
    const float* f4 = (const float*)d_in[5];
    const int* FPS0 = (const int*)d_in[6];
    const int* FPS1 = (const int*)d_in[7];
    const int* FPS2 = (const int*)d_in[8];
    const int* FPS3 = (const int*)d_in[9];
    const float* w04 = (const float*)d_in[10];
    const float* g04 = (const float*)d_in[12];
    const float* be04 = (const float*)d_in[13];
    const float* w14 = (const float*)d_in[14];
    const float* g14 = (const float*)d_in[16];
    const float* be14 = (const float*)d_in[17];
    const float* w24 = (const float*)d_in[18];
    const float* g24 = (const float*)d_in[20];
    const float* be24 = (const float*)d_in[21];
    const float* w34 = (const float*)d_in[22];
    const float* g34 = (const float*)d_in[24];
    const float* be34 = (const float*)d_in[25];
    const float* w4 = (const float*)d_in[26];
    const float* g4 = (const float*)d_in[28];
    const float* be4 = (const float*)d_in[29];

    float* out = (float*)d_out;

    // workspace: Y0..Y3 bf16, rowidx [4][8192], sums [5][2][1024]
    const size_t YN = (size_t)8192 * 1024;
    bf16* Y0 = (bf16*)d_ws;
    bf16* Y1 = Y0 + YN;
    bf16* Y2 = Y1 + YN;
    bf16* Y3 = Y2 + YN;
    int* rowidx = (int*)(Y3 + YN);
    float* sums = (float*)(rowidx + 4 * 8192);
    bf16* X4 = Y0;   // alias: Y0 consumed elementwise before overwrite (combine_k)
    bf16* Y4 = Y1;   // alias: Y1 dead after combine_k

    // bf16 scratch (gathered A + converted W) in out-region 4: dead until
    // final2_k overwrites it (after gemm4_k's W reads, ordered by kernel boundary).
    float* out4 = out + (size_t)4 * 8388608;
    bf16* Ab = (bf16*)out4;
    bf16* Wb = Ab + (size_t)8192 * 960;
    const bf16* W4 = Wb + (size_t)1024 * 960;   // level-4 weight slice

    if (ws_size < (size_t)(4 * YN * 2 + 4 * 8192 * 4 + 5 * 2048 * 4)) return;

    // 1) index chains + zero sums
    idx_k<<<64, 128, 0, stream>>>(FPS0, FPS1, FPS2, FPS3, rowidx, sums);

    // 2) gather + convert (A levels 0-3, W levels 0-4)
    gather_k<<<dim3(2048, 9), 256, 0, stream>>>(f0, f1, f2, f3,
                                                w04, w14, w24, w34, w4,
                                                rowidx, Ab, Wb);

    // 3) levels 0-3 GEMM with copy passthrough INTERLEAVED (role = lgc%5)
    gemm16_k<<<2560, 256, 0, stream>>>(Ab, Wb, Y0, sums,
                                       f0, f1, f2, f3, out);

    // 4) combine (inline BN finalize for levels 0-3)
    combine_k<<<1024, 256, 0, stream>>>(Y0, Y1, Y2, Y3, f4, sums,
                                        g04, be04, g14, be14, g24, be24,
                                        g34, be34, X4);

    // 5) level-4 GEMM (plain): Y4 + BN sums
    gemm4_k<<<512, 256, 0, stream>>>(X4, W4, Y4, sums + 4 * 2048);

    // 6) finalize inline + apply + residual -> f32 out
    final2_k<<<1024, 256, 0, stream>>>(Y4, f4, sums + 4 * 2048, g4, be4, out4);
}